// Round 2
// baseline (1485.051 us; speedup 1.0000x reference)
//
#include <hip/hip_runtime.h>
#include <hip/hip_bf16.h>

#define N_NODES 10000
#define N_EDGES 70000
#define HEADS 6
#define SELU_SCALE 1.0507009873554805f
#define SELU_ALPHA  1.6732632423543772f
#define NEG_SLOPE 0.2f

__device__ __forceinline__ float selu_f(float x) {
    return x > 0.f ? SELU_SCALE * x : SELU_SCALE * SELU_ALPHA * (__expf(x) - 1.f);
}

// ---------------- CSR build ----------------
__global__ void count_edges_k(const int* __restrict__ dstv, int* __restrict__ counts) {
    int e = blockIdx.x * blockDim.x + threadIdx.x;
    if (e < N_EDGES) atomicAdd(&counts[dstv[e]], 1);
}

__global__ __launch_bounds__(1024) void scan_k(const int* __restrict__ counts, int* __restrict__ offs) {
    __shared__ int part[1024];
    int tid = threadIdx.x;
    const int per = (N_NODES + 1023) / 1024;  // 10
    int start = tid * per;
    int s = 0;
    for (int i = 0; i < per; ++i) { int idx = start + i; if (idx < N_NODES) s += counts[idx]; }
    part[tid] = s;
    __syncthreads();
    for (int off = 1; off < 1024; off <<= 1) {
        int v = (tid >= off) ? part[tid - off] : 0;
        __syncthreads();
        part[tid] += v;
        __syncthreads();
    }
    int run = part[tid] - s;  // exclusive base for this chunk
    for (int i = 0; i < per; ++i) {
        int idx = start + i;
        if (idx < N_NODES) { offs[idx] = run; run += counts[idx]; }
    }
    if (tid == 0) offs[N_NODES] = part[1023];
}

__global__ void fill_csr_k(const int* __restrict__ dstv, const int* __restrict__ offs,
                           int* __restrict__ cursor, int* __restrict__ csr) {
    int e = blockIdx.x * blockDim.x + threadIdx.x;
    if (e < N_EDGES) {
        int d = dstv[e];
        int pos = atomicAdd(&cursor[d], 1);
        csr[offs[d] + pos] = e;
    }
}

// ---------------- input prep ----------------
__global__ void init_coords_k(const float* __restrict__ data, float* __restrict__ coords0,
                              float* __restrict__ t1) {
    int n = blockIdx.x * blockDim.x + threadIdx.x;
    if (n < N_NODES) {
        float x = data[n * 10 + 0], y = data[n * 10 + 1];
        coords0[2 * n] = x; coords0[2 * n + 1] = y;
        t1[(size_t)n * 256 + 0] = x; t1[(size_t)n * 256 + 1] = y;
    }
}

__global__ void lin_k(const float* __restrict__ data, const float* __restrict__ W,
                      const float* __restrict__ b, float* __restrict__ t1) {
    int idx = blockIdx.x * blockDim.x + threadIdx.x;
    if (idx >= N_NODES * 254) return;
    int n = idx / 254, c = idx % 254;
    float acc = b[c];
    const float* dr = data + (size_t)n * 10;
#pragma unroll
    for (int k = 0; k < 10; ++k) acc += dr[k] * W[k * 254 + c];
    t1[(size_t)n * 256 + 2 + c] = selu_f(acc);
}

// ---------------- GEMM (fp32, 64x64 tile, 4x4 per thread) ----------------
#define BM 64
#define BN 64
#define BK 16
__global__ __launch_bounds__(256) void gemm_f32(const float* __restrict__ A,
                                                const float* __restrict__ B,
                                                float* __restrict__ C,
                                                int M, int N, int K) {
    __shared__ __align__(16) float As[BK][BM + 1];
    __shared__ __align__(16) float Bs[BK][BN + 4];
    int tid = threadIdx.x;
    int tx = tid % 16, ty = tid / 16;
    int row0 = blockIdx.y * BM, col0 = blockIdx.x * BN;
    float acc[4][4] = {};
    int l = tid * 4;
    int ar = l / BK, ak = l % BK;       // A tile coords
    int br = l / BN, bc = l % BN;       // B tile coords
    for (int kt = 0; kt < K; kt += BK) {
        float4 av = make_float4(0.f, 0.f, 0.f, 0.f);
        if (row0 + ar < M) av = *(const float4*)&A[(size_t)(row0 + ar) * K + kt + ak];
        As[ak + 0][ar] = av.x; As[ak + 1][ar] = av.y;
        As[ak + 2][ar] = av.z; As[ak + 3][ar] = av.w;
        float4 bv = make_float4(0.f, 0.f, 0.f, 0.f);
        if (col0 + bc < N) bv = *(const float4*)&B[(size_t)(kt + br) * N + col0 + bc];
        *(float4*)&Bs[br][bc] = bv;
        __syncthreads();
#pragma unroll
        for (int kk = 0; kk < BK; ++kk) {
            float a[4], b[4];
#pragma unroll
            for (int i = 0; i < 4; ++i) a[i] = As[kk][ty * 4 + i];
#pragma unroll
            for (int j = 0; j < 4; ++j) b[j] = Bs[kk][tx * 4 + j];
#pragma unroll
            for (int i = 0; i < 4; ++i)
#pragma unroll
                for (int j = 0; j < 4; ++j) acc[i][j] += a[i] * b[j];
        }
        __syncthreads();
    }
#pragma unroll
    for (int i = 0; i < 4; ++i) {
        int r = row0 + ty * 4 + i;
        if (r >= M) break;
#pragma unroll
        for (int j = 0; j < 4; ++j) {
            int c = col0 + tx * 4 + j;
            if (c < N) C[(size_t)r * N + c] = acc[i][j];
        }
    }
}

// ---------------- attention ----------------
// Fold a_src/a_dst into W: wf[k*6+h] = sum_c W[k, h*C + c] * avec[h*C + c]
__global__ void fold_k(const float* __restrict__ W, const float* __restrict__ avec,
                       float* __restrict__ wf, int K, int C) {
    int idx = blockIdx.x * blockDim.x + threadIdx.x;
    if (idx >= K * HEADS) return;
    int k = idx / HEADS, h = idx % HEADS;
    const float* wr = W + (size_t)k * (HEADS * C) + h * C;
    const float* ar = avec + h * C;
    float acc = 0.f;
    for (int c = 0; c < C; ++c) acc += wr[c] * ar[c];
    wf[idx] = acc;
}

__global__ void proj_k(const float* __restrict__ t, const float* __restrict__ wsf,
                       const float* __restrict__ wdf, float* __restrict__ a_s,
                       float* __restrict__ a_d, int K) {
    int idx = blockIdx.x * blockDim.x + threadIdx.x;
    if (idx >= N_NODES * HEADS) return;
    int n = idx / HEADS, h = idx % HEADS;
    const float* tr = t + (size_t)n * K;
    float s = 0.f, d = 0.f;
    for (int k = 0; k < K; ++k) {
        float v = tr[k];
        s += v * wsf[k * HEADS + h];
        d += v * wdf[k * HEADS + h];
    }
    a_s[idx] = s; a_d[idx] = d;
}

__global__ void edge_logits_k(const int* __restrict__ srcv, const int* __restrict__ dstv,
                              const float* __restrict__ a_s, const float* __restrict__ a_d,
                              float* __restrict__ earr) {
    int idx = blockIdx.x * blockDim.x + threadIdx.x;
    if (idx >= N_EDGES * HEADS) return;
    int e = idx / HEADS, h = idx % HEADS;
    float v = a_s[srcv[e] * HEADS + h] + a_d[dstv[e] * HEADS + h];
    earr[idx] = v > 0.f ? v : NEG_SLOPE * v;
}

__global__ void softmax_k(const float* __restrict__ earr, const int* __restrict__ csr,
                          const int* __restrict__ offs, float* __restrict__ alpha) {
    int idx = blockIdx.x * blockDim.x + threadIdx.x;
    if (idx >= N_NODES * HEADS) return;
    int n = idx / HEADS, h = idx % HEADS;
    int r0 = offs[n], r1 = offs[n + 1];
    if (r0 == r1) return;
    float m = -1e30f;
    for (int i = r0; i < r1; ++i) m = fmaxf(m, earr[csr[i] * HEADS + h]);
    float denom = 0.f;
    for (int i = r0; i < r1; ++i) {
        float ex = __expf(earr[csr[i] * HEADS + h] - m);
        alpha[csr[i] * HEADS + h] = ex;
        denom += ex;
    }
    float rd = 1.f / denom;
    for (int i = r0; i < r1; ++i) alpha[csr[i] * HEADS + h] *= rd;
}

// ---------------- aggregation ----------------
__global__ __launch_bounds__(256) void aggregate_k(const float* __restrict__ x,
                                                   const float* __restrict__ alpha,
                                                   const int* __restrict__ csr,
                                                   const int* __restrict__ offs,
                                                   const int* __restrict__ srcv,
                                                   float* __restrict__ tout,
                                                   int C, int ld, int off) {
    int n = blockIdx.x;
    int c = blockIdx.y * 256 + threadIdx.x;
    if (c >= C) return;
    int HC = HEADS * C;
    float acc = 0.f;
    int r0 = offs[n], r1 = offs[n + 1];
    for (int i = r0; i < r1; ++i) {
        int ee = csr[i];
        int s = srcv[ee];
        const float* xr = x + (size_t)s * HC + c;
        const float* al = alpha + (size_t)ee * HEADS;
#pragma unroll
        for (int h = 0; h < HEADS; ++h) acc += al[h] * xr[h * C];
    }
    tout[(size_t)n * ld + off + c] = selu_f(acc * (1.f / 6.f));
}

__global__ void move_coords_k(const float* __restrict__ cprev, const float* __restrict__ alpha,
                              const int* __restrict__ csr, const int* __restrict__ offs,
                              const int* __restrict__ srcv, const int* __restrict__ bd,
                              float* __restrict__ cout, float* __restrict__ tnext,
                              int ld, int off) {
    int n = blockIdx.x * blockDim.x + threadIdx.x;
    if (n >= N_NODES) return;
    float cx, cy;
    if (bd[n] != 0) {
        cx = cprev[2 * n]; cy = cprev[2 * n + 1];
    } else {
        cx = 0.f; cy = 0.f;
        int r0 = offs[n], r1 = offs[n + 1];
        for (int i = r0; i < r1; ++i) {
            int ee = csr[i];
            int s = srcv[ee];
            const float* al = alpha + (size_t)ee * HEADS;
            float am = (al[0] + al[1] + al[2] + al[3] + al[4] + al[5]) * (1.f / 6.f);
            cx += am * cprev[2 * s];
            cy += am * cprev[2 * s + 1];
        }
    }
    cout[2 * n] = cx; cout[2 * n + 1] = cy;
    if (tnext) {
        tnext[(size_t)n * ld + off + 0] = cx;
        tnext[(size_t)n * ld + off + 1] = cy;
    }
}

__global__ void copy2_k(const float* __restrict__ srcc, float* __restrict__ t, int ld, int off) {
    int n = blockIdx.x * blockDim.x + threadIdx.x;
    if (n < N_NODES) {
        t[(size_t)n * ld + off + 0] = srcc[2 * n];
        t[(size_t)n * ld + off + 1] = srcc[2 * n + 1];
    }
}

static inline int cdiv(int a, int b) { return (a + b - 1) / b; }

extern "C" void kernel_launch(void* const* d_in, const int* in_sizes, int n_in,
                              void* d_out, int out_size, void* d_ws, size_t ws_size,
                              hipStream_t stream) {
    const float* data = (const float*)d_in[0];
    const int* eidx = (const int*)d_in[1];
    const int* bd = (const int*)d_in[2];      // bool input arrives as int32
    const float* W_lin = (const float*)d_in[4];
    const float* b_lin = (const float*)d_in[5];
    const float* Wl[4]  = {(const float*)d_in[6],  (const float*)d_in[9],
                           (const float*)d_in[12], (const float*)d_in[15]};
    const float* Asrc[4] = {(const float*)d_in[7],  (const float*)d_in[10],
                            (const float*)d_in[13], (const float*)d_in[16]};
    const float* Adst[4] = {(const float*)d_in[8],  (const float*)d_in[11],
                            (const float*)d_in[14], (const float*)d_in[17]};
    const int Kd[4] = {256, 512, 256, 128};
    const int Cd[4] = {508, 250, 120, 20};

    const int* srcv = eidx;
    const int* dstv = eidx + N_EDGES;

    // workspace carve
    char* p = (char*)d_ws;
    auto alloc = [&](size_t bytes) -> void* {
        void* r = (void*)p;
        p += (bytes + 255) & ~(size_t)255;
        return r;
    };
    float* t1 = (float*)alloc((size_t)N_NODES * 256 * 4);
    float* t2 = (float*)alloc((size_t)N_NODES * 512 * 4);
    float* t3 = (float*)alloc((size_t)N_NODES * 256 * 4);
    float* t4 = (float*)alloc((size_t)N_NODES * 128 * 4);
    float* xbuf = (float*)alloc((size_t)N_NODES * 3048 * 4);
    float* coords0 = (float*)alloc((size_t)N_NODES * 2 * 4);
    float* c1 = (float*)alloc((size_t)N_NODES * 2 * 4);
    float* c2 = (float*)alloc((size_t)N_NODES * 2 * 4);
    float* c3 = (float*)alloc((size_t)N_NODES * 2 * 4);
    float* a_s = (float*)alloc((size_t)N_NODES * HEADS * 4);
    float* a_d = (float*)alloc((size_t)N_NODES * HEADS * 4);
    float* earr = (float*)alloc((size_t)N_EDGES * HEADS * 4);
    float* alpha = (float*)alloc((size_t)N_EDGES * HEADS * 4);
    float* wsf = (float*)alloc((size_t)512 * HEADS * 4);
    float* wdf = (float*)alloc((size_t)512 * HEADS * 4);
    int* counts = (int*)alloc((size_t)N_NODES * 4);
    int* offs = (int*)alloc((size_t)(N_NODES + 1) * 4);
    int* cursor = (int*)alloc((size_t)N_NODES * 4);
    int* csr = (int*)alloc((size_t)N_EDGES * 4);

    // CSR build (deterministic work each call)
    hipMemsetAsync(counts, 0, N_NODES * sizeof(int), stream);
    hipMemsetAsync(cursor, 0, N_NODES * sizeof(int), stream);
    count_edges_k<<<cdiv(N_EDGES, 256), 256, 0, stream>>>(dstv, counts);
    scan_k<<<1, 1024, 0, stream>>>(counts, offs);
    fill_csr_k<<<cdiv(N_EDGES, 256), 256, 0, stream>>>(dstv, offs, cursor, csr);

    // input prep: t1 = [coords, selu(data@W_lin+b)]
    init_coords_k<<<cdiv(N_NODES, 256), 256, 0, stream>>>(data, coords0, t1);
    lin_k<<<cdiv(N_NODES * 254, 256), 256, 0, stream>>>(data, W_lin, b_lin, t1);

    float* tin[4]   = {t1, t2, t3, t4};
    float* tnext[4] = {t2, t3, t4, nullptr};
    int ldn[4]  = {512, 256, 128, 0};
    int foff[4] = {4, 6, 8, 0};
    float* cprev[4] = {coords0, c1, c2, c3};
    float* cout[4]  = {c1, c2, c3, (float*)d_out};

    for (int l = 0; l < 4; ++l) {
        int K = Kd[l], C = Cd[l], HC = HEADS * C;
        // folded attention weights + projections (no x needed)
        fold_k<<<cdiv(K * HEADS, 256), 256, 0, stream>>>(Wl[l], Asrc[l], wsf, K, C);
        fold_k<<<cdiv(K * HEADS, 256), 256, 0, stream>>>(Wl[l], Adst[l], wdf, K, C);
        proj_k<<<cdiv(N_NODES * HEADS, 256), 256, 0, stream>>>(tin[l], wsf, wdf, a_s, a_d, K);
        edge_logits_k<<<cdiv(N_EDGES * HEADS, 256), 256, 0, stream>>>(srcv, dstv, a_s, a_d, earr);
        softmax_k<<<cdiv(N_NODES * HEADS, 256), 256, 0, stream>>>(earr, csr, offs, alpha);

        if (l < 3) {
            // x = tin @ W  (needed for feature aggregation only)
            gemm_f32<<<dim3(cdiv(HC, BN), cdiv(N_NODES, BM)), 256, 0, stream>>>(
                tin[l], Wl[l], xbuf, N_NODES, HC, K);
            aggregate_k<<<dim3(N_NODES, cdiv(C, 256)), 256, 0, stream>>>(
                xbuf, alpha, csr, offs, srcv, tnext[l], C, ldn[l], foff[l]);
        }
        move_coords_k<<<cdiv(N_NODES, 256), 256, 0, stream>>>(
            cprev[l], alpha, csr, offs, srcv, bd, cout[l], tnext[l], ldn[l], 0);
        // assemble remaining coord columns of the next t buffer
        if (l == 0) {
            copy2_k<<<cdiv(N_NODES, 256), 256, 0, stream>>>(coords0, t2, 512, 2);
        } else if (l == 1) {
            copy2_k<<<cdiv(N_NODES, 256), 256, 0, stream>>>(c1, t3, 256, 2);
            copy2_k<<<cdiv(N_NODES, 256), 256, 0, stream>>>(coords0, t3, 256, 4);
        } else if (l == 2) {
            copy2_k<<<cdiv(N_NODES, 256), 256, 0, stream>>>(c2, t4, 128, 2);
            copy2_k<<<cdiv(N_NODES, 256), 256, 0, stream>>>(c1, t4, 128, 4);
            copy2_k<<<cdiv(N_NODES, 256), 256, 0, stream>>>(coords0, t4, 128, 6);
        }
    }
}

// Round 3
// 988.738 us; speedup vs baseline: 1.5020x; 1.5020x over previous
//
#include <hip/hip_runtime.h>
#include <hip/hip_bf16.h>

#define N_NODES 10000
#define N_EDGES 70000
#define HEADS 6
#define MPAD 10112            // ceil(10000/128)*128
#define SELU_SCALE 1.0507009873554805f
#define SELU_ALPHA  1.6732632423543772f
#define NEG_SLOPE 0.2f

typedef __attribute__((ext_vector_type(8))) __bf16 bf16x8;
typedef __attribute__((ext_vector_type(4))) float f32x4;

__device__ __forceinline__ float selu_f(float x) {
    return x > 0.f ? SELU_SCALE * x : SELU_SCALE * SELU_ALPHA * (__expf(x) - 1.f);
}
__device__ __forceinline__ unsigned short f2bf(float f) {
    __hip_bfloat16 h = __float2bfloat16(f);
    return __builtin_bit_cast(unsigned short, h);
}
__device__ __forceinline__ float bf2f(unsigned short u) {
    unsigned int x = ((unsigned int)u) << 16;
    return __builtin_bit_cast(float, x);
}

// ---------------- CSR build ----------------
__global__ void count_edges_k(const int* __restrict__ dstv, int* __restrict__ counts) {
    int e = blockIdx.x * blockDim.x + threadIdx.x;
    if (e < N_EDGES) atomicAdd(&counts[dstv[e]], 1);
}

__global__ __launch_bounds__(1024) void scan_k(const int* __restrict__ counts, int* __restrict__ offs) {
    __shared__ int part[1024];
    int tid = threadIdx.x;
    const int per = (N_NODES + 1023) / 1024;  // 10
    int start = tid * per;
    int s = 0;
    for (int i = 0; i < per; ++i) { int idx = start + i; if (idx < N_NODES) s += counts[idx]; }
    part[tid] = s;
    __syncthreads();
    for (int off = 1; off < 1024; off <<= 1) {
        int v = (tid >= off) ? part[tid - off] : 0;
        __syncthreads();
        part[tid] += v;
        __syncthreads();
    }
    int run = part[tid] - s;
    for (int i = 0; i < per; ++i) {
        int idx = start + i;
        if (idx < N_NODES) { offs[idx] = run; run += counts[idx]; }
    }
    if (tid == 0) offs[N_NODES] = part[1023];
}

__global__ void fill_csr_k(const int* __restrict__ dstv, const int* __restrict__ offs,
                           int* __restrict__ cursor, int* __restrict__ csr) {
    int e = blockIdx.x * blockDim.x + threadIdx.x;
    if (e < N_EDGES) {
        int d = dstv[e];
        int pos = atomicAdd(&cursor[d], 1);
        csr[offs[d] + pos] = e;
    }
}

// ---------------- input prep ----------------
__global__ void init_coords_k(const float* __restrict__ data, float* __restrict__ coords0,
                              unsigned short* __restrict__ t1) {
    int n = blockIdx.x * blockDim.x + threadIdx.x;
    if (n < N_NODES) {
        float x = data[n * 10 + 0], y = data[n * 10 + 1];
        coords0[2 * n] = x; coords0[2 * n + 1] = y;
        t1[(size_t)n * 256 + 0] = f2bf(x); t1[(size_t)n * 256 + 1] = f2bf(y);
    }
}

__global__ void lin_k(const float* __restrict__ data, const float* __restrict__ W,
                      const float* __restrict__ b, unsigned short* __restrict__ t1) {
    int idx = blockIdx.x * blockDim.x + threadIdx.x;
    if (idx >= N_NODES * 254) return;
    int n = idx / 254, c = idx % 254;
    float acc = b[c];
    const float* dr = data + (size_t)n * 10;
#pragma unroll
    for (int k = 0; k < 10; ++k) acc += dr[k] * W[k * 254 + c];
    t1[(size_t)n * 256 + 2 + c] = f2bf(selu_f(acc));
}

// ---------------- W convert+transpose: W[K][HC] f32 -> Wt[Npad][K] bf16 ----------------
__global__ void convw_k(const float* __restrict__ W, unsigned short* __restrict__ Wt,
                        int K, int HC, int Npad) {
    int idx = blockIdx.x * blockDim.x + threadIdx.x;
    if (idx >= K * Npad) return;
    int k = idx / Npad, n = idx % Npad;           // coalesced read of W row
    float v = (n < HC) ? W[(size_t)k * HC + n] : 0.f;
    Wt[(size_t)n * K + k] = f2bf(v);
}

// ---------------- bf16 MFMA GEMM: C[Mpad][Npad] = A[Mpad][K] * Wt[Npad][K]^T ----------------
// 128x128 tile, BK=64, 4 waves (2x2 of 64x64), swapped operands so each lane
// holds 4 contiguous output columns. LDS XOR-swizzled (slot ^= row&7), sources
// pre-swizzled for linear global_load_lds writes.
__global__ __launch_bounds__(256) void gemm_bf16_mfma(
    const unsigned short* __restrict__ A,   // bf16 [MPAD][K]
    const unsigned short* __restrict__ Bt,  // bf16 [Npad][K]
    unsigned short* __restrict__ C,         // bf16 [MPAD][ldc]
    int K, int ldc) {
    __shared__ unsigned short lds[16384];   // 32 KB: A tile [128][64] + B tile [128][64]
    const int tid = threadIdx.x;
    const int lane = tid & 63, wid = tid >> 6;
    const int wm = wid >> 1, wn = wid & 1;
    const int m0 = blockIdx.y * 128;
    const int n0 = blockIdx.x * 128;

    f32x4 acc[4][4] = {};   // acc[fm][fn]

    // staging descriptors: 8 issues x 256 lanes x 16B = 8 KB... (4 for A, 4 for B)
    const unsigned short* gsrc[8];
    unsigned ldsoff[8];
#pragma unroll
    for (int i = 0; i < 8; ++i) {
        const int half = i >> 2;                    // 0 = A-tile, 1 = B-tile
        const int slot = (i & 3) * 256 + tid;       // 16B slot within tile
        const int r = slot >> 3;                    // tile row (0..127)
        const int c16 = slot & 7;                   // 16B column slot
        const int ksl = c16 ^ (r & 7);              // inverse-swizzled source k-slot
        gsrc[i] = (half ? (Bt + (size_t)(n0 + r) * K) : (A + (size_t)(m0 + r) * K)) + ksl * 8;
        ldsoff[i] = (unsigned)(half * 8192 + ((i & 3) * 256 + wid * 64) * 8);
    }

    for (int kt = 0; kt < K; kt += 64) {
#pragma unroll
        for (int i = 0; i < 8; ++i) {
            __builtin_amdgcn_global_load_lds(
                (const __attribute__((address_space(1))) unsigned int*)(gsrc[i] + kt),
                (__attribute__((address_space(3))) unsigned int*)(&lds[ldsoff[i]]),
                16, 0, 0);
        }
        __syncthreads();   // drains vmcnt: tiles resident
#pragma unroll
        for (int kc = 0; kc < 2; ++kc) {
            const int xo = (((kc * 4 + (lane >> 4)) ^ (lane & 7)) << 4);  // byte offset in row
            bf16x8 aop[4], bop[4];
#pragma unroll
            for (int f = 0; f < 4; ++f) {
                const int rA = wm * 64 + f * 16 + (lane & 15);
                bop[f] = *(const bf16x8*)((const char*)lds + rA * 128 + xo);
                const int rB = wn * 64 + f * 16 + (lane & 15);
                aop[f] = *(const bf16x8*)((const char*)lds + 16384 * 1 + rB * 128 + xo);
            }
#pragma unroll
            for (int fm = 0; fm < 4; ++fm)
#pragma unroll
                for (int fn = 0; fn < 4; ++fn)
                    acc[fm][fn] = __builtin_amdgcn_mfma_f32_16x16x32_bf16(
                        aop[fn], bop[fm], acc[fm][fn], 0, 0, 0);
        }
        __syncthreads();   // protect LDS before next stage
    }

    // store: lane holds rows m (=col of D), 4 contiguous n per frag
    const int mrow = m0 + wm * 64 + (lane & 15);
    const int ncol = n0 + wn * 64 + ((lane >> 4) * 4);
#pragma unroll
    for (int fm = 0; fm < 4; ++fm) {
#pragma unroll
        for (int fn = 0; fn < 4; ++fn) {
            f32x4 v = acc[fm][fn];
            unsigned int u0 = f2bf(v.x) | ((unsigned int)f2bf(v.y) << 16);
            unsigned int u1 = f2bf(v.z) | ((unsigned int)f2bf(v.w) << 16);
            uint2 pk = make_uint2(u0, u1);
            *(uint2*)&C[(size_t)(mrow + fm * 16) * ldc + ncol + fn * 16] = pk;
        }
    }
}

// ---------------- attention ----------------
__global__ void fold_k(const float* __restrict__ W, const float* __restrict__ avec,
                       float* __restrict__ wf, int K, int C) {
    int idx = blockIdx.x * blockDim.x + threadIdx.x;
    if (idx >= K * HEADS) return;
    int k = idx / HEADS, h = idx % HEADS;
    const float* wr = W + (size_t)k * (HEADS * C) + h * C;
    const float* ar = avec + h * C;
    float acc = 0.f;
    for (int c = 0; c < C; ++c) acc += wr[c] * ar[c];
    wf[idx] = acc;
}

__global__ void proj_k(const unsigned short* __restrict__ t, const float* __restrict__ wsf,
                       const float* __restrict__ wdf, float* __restrict__ a_s,
                       float* __restrict__ a_d, int K) {
    int idx = blockIdx.x * blockDim.x + threadIdx.x;
    if (idx >= N_NODES * HEADS) return;
    int n = idx / HEADS, h = idx % HEADS;
    const unsigned short* tr = t + (size_t)n * K;
    float s = 0.f, d = 0.f;
    for (int k = 0; k < K; ++k) {
        float v = bf2f(tr[k]);
        s += v * wsf[k * HEADS + h];
        d += v * wdf[k * HEADS + h];
    }
    a_s[idx] = s; a_d[idx] = d;
}

__global__ void edge_logits_k(const int* __restrict__ srcv, const int* __restrict__ dstv,
                              const float* __restrict__ a_s, const float* __restrict__ a_d,
                              float* __restrict__ earr) {
    int idx = blockIdx.x * blockDim.x + threadIdx.x;
    if (idx >= N_EDGES * HEADS) return;
    int e = idx / HEADS, h = idx % HEADS;
    float v = a_s[srcv[e] * HEADS + h] + a_d[dstv[e] * HEADS + h];
    earr[idx] = v > 0.f ? v : NEG_SLOPE * v;
}

__global__ void softmax_k(const float* __restrict__ earr, const int* __restrict__ csr,
                          const int* __restrict__ offs, float* __restrict__ alpha) {
    int idx = blockIdx.x * blockDim.x + threadIdx.x;
    if (idx >= N_NODES * HEADS) return;
    int n = idx / HEADS, h = idx % HEADS;
    int r0 = offs[n], r1 = offs[n + 1];
    if (r0 == r1) return;
    float m = -1e30f;
    for (int i = r0; i < r1; ++i) m = fmaxf(m, earr[csr[i] * HEADS + h]);
    float denom = 0.f;
    for (int i = r0; i < r1; ++i) {
        float ex = __expf(earr[csr[i] * HEADS + h] - m);
        alpha[csr[i] * HEADS + h] = ex;
        denom += ex;
    }
    float rd = 1.f / denom;
    for (int i = r0; i < r1; ++i) alpha[csr[i] * HEADS + h] *= rd;
}

// ---------------- aggregation (x in bf16) ----------------
__global__ __launch_bounds__(256) void aggregate_k(const unsigned short* __restrict__ x,
                                                   const float* __restrict__ alpha,
                                                   const int* __restrict__ csr,
                                                   const int* __restrict__ offs,
                                                   const int* __restrict__ srcv,
                                                   unsigned short* __restrict__ tout,
                                                   int C, int ldx, int ld, int off) {
    int n = blockIdx.x;
    int c = blockIdx.y * 256 + threadIdx.x;
    if (c >= C) return;
    float acc = 0.f;
    int r0 = offs[n], r1 = offs[n + 1];
    for (int i = r0; i < r1; ++i) {
        int ee = csr[i];
        int s = srcv[ee];
        const unsigned short* xr = x + (size_t)s * ldx + c;
        const float* al = alpha + (size_t)ee * HEADS;
#pragma unroll
        for (int h = 0; h < HEADS; ++h) acc += al[h] * bf2f(xr[h * C]);
    }
    tout[(size_t)n * ld + off + c] = f2bf(selu_f(acc * (1.f / 6.f)));
}

__global__ void move_coords_k(const float* __restrict__ cprev, const float* __restrict__ alpha,
                              const int* __restrict__ csr, const int* __restrict__ offs,
                              const int* __restrict__ srcv, const int* __restrict__ bd,
                              float* __restrict__ cout, unsigned short* __restrict__ tnext,
                              int ld, int off) {
    int n = blockIdx.x * blockDim.x + threadIdx.x;
    if (n >= N_NODES) return;
    float cx, cy;
    if (bd[n] != 0) {
        cx = cprev[2 * n]; cy = cprev[2 * n + 1];
    } else {
        cx = 0.f; cy = 0.f;
        int r0 = offs[n], r1 = offs[n + 1];
        for (int i = r0; i < r1; ++i) {
            int ee = csr[i];
            int s = srcv[ee];
            const float* al = alpha + (size_t)ee * HEADS;
            float am = (al[0] + al[1] + al[2] + al[3] + al[4] + al[5]) * (1.f / 6.f);
            cx += am * cprev[2 * s];
            cy += am * cprev[2 * s + 1];
        }
    }
    cout[2 * n] = cx; cout[2 * n + 1] = cy;
    if (tnext) {
        tnext[(size_t)n * ld + off + 0] = f2bf(cx);
        tnext[(size_t)n * ld + off + 1] = f2bf(cy);
    }
}

__global__ void copy2_k(const float* __restrict__ srcc, unsigned short* __restrict__ t,
                        int ld, int off) {
    int n = blockIdx.x * blockDim.x + threadIdx.x;
    if (n < N_NODES) {
        t[(size_t)n * ld + off + 0] = f2bf(srcc[2 * n]);
        t[(size_t)n * ld + off + 1] = f2bf(srcc[2 * n + 1]);
    }
}

static inline int cdiv(int a, int b) { return (a + b - 1) / b; }

extern "C" void kernel_launch(void* const* d_in, const int* in_sizes, int n_in,
                              void* d_out, int out_size, void* d_ws, size_t ws_size,
                              hipStream_t stream) {
    const float* data = (const float*)d_in[0];
    const int* eidx = (const int*)d_in[1];
    const int* bd = (const int*)d_in[2];
    const float* W_lin = (const float*)d_in[4];
    const float* b_lin = (const float*)d_in[5];
    const float* Wl[4]  = {(const float*)d_in[6],  (const float*)d_in[9],
                           (const float*)d_in[12], (const float*)d_in[15]};
    const float* Asrc[4] = {(const float*)d_in[7],  (const float*)d_in[10],
                            (const float*)d_in[13], (const float*)d_in[16]};
    const float* Adst[4] = {(const float*)d_in[8],  (const float*)d_in[11],
                            (const float*)d_in[14], (const float*)d_in[17]};
    const int Kd[4] = {256, 512, 256, 128};
    const int Cd[4] = {508, 250, 120, 20};
    const int Npadd[4] = {3072, 1536, 768, 0};

    const int* srcv = eidx;
    const int* dstv = eidx + N_EDGES;

    char* p = (char*)d_ws;
    auto alloc = [&](size_t bytes) -> void* {
        void* r = (void*)p;
        p += (bytes + 255) & ~(size_t)255;
        return r;
    };
    unsigned short* tb1 = (unsigned short*)alloc((size_t)MPAD * 256 * 2);
    unsigned short* tb2 = (unsigned short*)alloc((size_t)MPAD * 512 * 2);
    unsigned short* tb3 = (unsigned short*)alloc((size_t)MPAD * 256 * 2);
    unsigned short* tb4 = (unsigned short*)alloc((size_t)MPAD * 128 * 2);
    unsigned short* xb  = (unsigned short*)alloc((size_t)MPAD * 3072 * 2);
    unsigned short* Wt  = (unsigned short*)alloc((size_t)3072 * 256 * 2); // max K*Npad
    float* coords0 = (float*)alloc((size_t)N_NODES * 2 * 4);
    float* c1 = (float*)alloc((size_t)N_NODES * 2 * 4);
    float* c2 = (float*)alloc((size_t)N_NODES * 2 * 4);
    float* c3 = (float*)alloc((size_t)N_NODES * 2 * 4);
    float* a_s = (float*)alloc((size_t)N_NODES * HEADS * 4);
    float* a_d = (float*)alloc((size_t)N_NODES * HEADS * 4);
    float* earr = (float*)alloc((size_t)N_EDGES * HEADS * 4);
    float* alpha = (float*)alloc((size_t)N_EDGES * HEADS * 4);
    float* wsf = (float*)alloc((size_t)512 * HEADS * 4);
    float* wdf = (float*)alloc((size_t)512 * HEADS * 4);
    int* counts = (int*)alloc((size_t)N_NODES * 4);
    int* offs = (int*)alloc((size_t)(N_NODES + 1) * 4);
    int* cursor = (int*)alloc((size_t)N_NODES * 4);
    int* csr = (int*)alloc((size_t)N_EDGES * 4);

    hipMemsetAsync(counts, 0, N_NODES * sizeof(int), stream);
    hipMemsetAsync(cursor, 0, N_NODES * sizeof(int), stream);
    count_edges_k<<<cdiv(N_EDGES, 256), 256, 0, stream>>>(dstv, counts);
    scan_k<<<1, 1024, 0, stream>>>(counts, offs);
    fill_csr_k<<<cdiv(N_EDGES, 256), 256, 0, stream>>>(dstv, offs, cursor, csr);

    init_coords_k<<<cdiv(N_NODES, 256), 256, 0, stream>>>(data, coords0, tb1);
    lin_k<<<cdiv(N_NODES * 254, 256), 256, 0, stream>>>(data, W_lin, b_lin, tb1);

    unsigned short* tin[4]   = {tb1, tb2, tb3, tb4};
    unsigned short* tnext[4] = {tb2, tb3, tb4, nullptr};
    int ldn[4]  = {512, 256, 128, 0};
    int foff[4] = {4, 6, 8, 0};
    float* cprev[4] = {coords0, c1, c2, c3};
    float* cout[4]  = {c1, c2, c3, (float*)d_out};

    for (int l = 0; l < 4; ++l) {
        int K = Kd[l], C = Cd[l], HC = HEADS * C, Npad = Npadd[l];
        fold_k<<<cdiv(K * HEADS, 256), 256, 0, stream>>>(Wl[l], Asrc[l], wsf, K, C);
        fold_k<<<cdiv(K * HEADS, 256), 256, 0, stream>>>(Wl[l], Adst[l], wdf, K, C);
        proj_k<<<cdiv(N_NODES * HEADS, 256), 256, 0, stream>>>(tin[l], wsf, wdf, a_s, a_d, K);
        edge_logits_k<<<cdiv(N_EDGES * HEADS, 256), 256, 0, stream>>>(srcv, dstv, a_s, a_d, earr);
        softmax_k<<<cdiv(N_NODES * HEADS, 256), 256, 0, stream>>>(earr, csr, offs, alpha);

        if (l < 3) {
            convw_k<<<cdiv(K * Npad, 256), 256, 0, stream>>>(Wl[l], Wt, K, HC, Npad);
            gemm_bf16_mfma<<<dim3(Npad / 128, MPAD / 128), 256, 0, stream>>>(
                tin[l], Wt, xb, K, Npad);
            aggregate_k<<<dim3(N_NODES, cdiv(C, 256)), 256, 0, stream>>>(
                xb, alpha, csr, offs, srcv, tnext[l], C, Npad, ldn[l], foff[l]);
        }
        move_coords_k<<<cdiv(N_NODES, 256), 256, 0, stream>>>(
            cprev[l], alpha, csr, offs, srcv, bd, cout[l], tnext[l], ldn[l], 0);
        if (l == 0) {
            copy2_k<<<cdiv(N_NODES, 256), 256, 0, stream>>>(coords0, tb2, 512, 2);
        } else if (l == 1) {
            copy2_k<<<cdiv(N_NODES, 256), 256, 0, stream>>>(c1, tb3, 256, 2);
            copy2_k<<<cdiv(N_NODES, 256), 256, 0, stream>>>(coords0, tb3, 256, 4);
        } else if (l == 2) {
            copy2_k<<<cdiv(N_NODES, 256), 256, 0, stream>>>(c2, tb4, 128, 2);
            copy2_k<<<cdiv(N_NODES, 256), 256, 0, stream>>>(c1, tb4, 128, 4);
            copy2_k<<<cdiv(N_NODES, 256), 256, 0, stream>>>(coords0, tb4, 128, 6);
        }
    }
}

// Round 4
// 672.469 us; speedup vs baseline: 2.2084x; 1.4703x over previous
//
#include <hip/hip_runtime.h>
#include <hip/hip_bf16.h>

#define N_NODES 10000
#define N_EDGES 70000
#define HEADS 6
#define MPAD 10112            // ceil(10000/128)*128
#define SELU_SCALE 1.0507009873554805f
#define SELU_ALPHA  1.6732632423543772f
#define NEG_SLOPE 0.2f

typedef __attribute__((ext_vector_type(8))) __bf16 bf16x8;
typedef __attribute__((ext_vector_type(4))) float f32x4;

__device__ __forceinline__ float selu_f(float x) {
    return x > 0.f ? SELU_SCALE * x : SELU_SCALE * SELU_ALPHA * (__expf(x) - 1.f);
}
__device__ __forceinline__ unsigned short f2bf(float f) {
    __hip_bfloat16 h = __float2bfloat16(f);
    return __builtin_bit_cast(unsigned short, h);
}
__device__ __forceinline__ float bf2f(unsigned short u) {
    unsigned int x = ((unsigned int)u) << 16;
    return __builtin_bit_cast(float, x);
}

// ---------------- CSR build ----------------
__global__ void count_edges_k(const int* __restrict__ dstv, int* __restrict__ counts) {
    int e = blockIdx.x * blockDim.x + threadIdx.x;
    if (e < N_EDGES) atomicAdd(&counts[dstv[e]], 1);
}

__global__ __launch_bounds__(1024) void scan_k(const int* __restrict__ counts, int* __restrict__ offs) {
    __shared__ int part[1024];
    int tid = threadIdx.x;
    const int per = (N_NODES + 1023) / 1024;  // 10
    int start = tid * per;
    int s = 0;
    for (int i = 0; i < per; ++i) { int idx = start + i; if (idx < N_NODES) s += counts[idx]; }
    part[tid] = s;
    __syncthreads();
    for (int off = 1; off < 1024; off <<= 1) {
        int v = (tid >= off) ? part[tid - off] : 0;
        __syncthreads();
        part[tid] += v;
        __syncthreads();
    }
    int run = part[tid] - s;
    for (int i = 0; i < per; ++i) {
        int idx = start + i;
        if (idx < N_NODES) { offs[idx] = run; run += counts[idx]; }
    }
    if (tid == 0) offs[N_NODES] = part[1023];
}

__global__ void fill_csr_k(const int* __restrict__ dstv, const int* __restrict__ offs,
                           int* __restrict__ cursor, int* __restrict__ csr) {
    int e = blockIdx.x * blockDim.x + threadIdx.x;
    if (e < N_EDGES) {
        int d = dstv[e];
        int pos = atomicAdd(&cursor[d], 1);
        csr[offs[d] + pos] = e;
    }
}

// ---------------- input prep ----------------
__global__ void init_coords_k(const float* __restrict__ data, float* __restrict__ coords0,
                              unsigned short* __restrict__ t1) {
    int n = blockIdx.x * blockDim.x + threadIdx.x;
    if (n < N_NODES) {
        float x = data[n * 10 + 0], y = data[n * 10 + 1];
        coords0[2 * n] = x; coords0[2 * n + 1] = y;
        t1[(size_t)n * 256 + 0] = f2bf(x); t1[(size_t)n * 256 + 1] = f2bf(y);
    }
}

__global__ void lin_k(const float* __restrict__ data, const float* __restrict__ W,
                      const float* __restrict__ b, unsigned short* __restrict__ t1) {
    int idx = blockIdx.x * blockDim.x + threadIdx.x;
    if (idx >= N_NODES * 254) return;
    int n = idx / 254, c = idx % 254;
    float acc = b[c];
    const float* dr = data + (size_t)n * 10;
#pragma unroll
    for (int k = 0; k < 10; ++k) acc += dr[k] * W[k * 254 + c];
    t1[(size_t)n * 256 + 2 + c] = f2bf(selu_f(acc));
}

// ---------------- W convert+transpose: W[K][HC] f32 -> Wt[Npad][K] bf16 ----------------
__global__ void convw_k(const float* __restrict__ W, unsigned short* __restrict__ Wt,
                        int K, int HC, int Npad) {
    int idx = blockIdx.x * blockDim.x + threadIdx.x;
    if (idx >= K * Npad) return;
    int k = idx / Npad, n = idx % Npad;           // coalesced read of W row
    float v = (n < HC) ? W[(size_t)k * HC + n] : 0.f;
    Wt[(size_t)n * K + k] = f2bf(v);
}

// ---------------- bf16 MFMA GEMM: C[Mpad][Npad] = A[Mpad][K] * Wt[Npad][K]^T ----------------
__global__ __launch_bounds__(256) void gemm_bf16_mfma(
    const unsigned short* __restrict__ A,   // bf16 [MPAD][K]
    const unsigned short* __restrict__ Bt,  // bf16 [Npad][K]
    unsigned short* __restrict__ C,         // bf16 [MPAD][ldc]
    int K, int ldc) {
    __shared__ unsigned short lds[16384];   // 32 KB: A tile [128][64] + B tile [128][64]
    const int tid = threadIdx.x;
    const int lane = tid & 63, wid = tid >> 6;
    const int wm = wid >> 1, wn = wid & 1;
    const int m0 = blockIdx.y * 128;
    const int n0 = blockIdx.x * 128;

    f32x4 acc[4][4] = {};   // acc[fm][fn]

    const unsigned short* gsrc[8];
    unsigned ldsoff[8];
#pragma unroll
    for (int i = 0; i < 8; ++i) {
        const int half = i >> 2;                    // 0 = A-tile, 1 = B-tile
        const int slot = (i & 3) * 256 + tid;       // 16B slot within tile
        const int r = slot >> 3;                    // tile row (0..127)
        const int c16 = slot & 7;                   // 16B column slot
        const int ksl = c16 ^ (r & 7);              // inverse-swizzled source k-slot
        gsrc[i] = (half ? (Bt + (size_t)(n0 + r) * K) : (A + (size_t)(m0 + r) * K)) + ksl * 8;
        ldsoff[i] = (unsigned)(half * 8192 + ((i & 3) * 256 + wid * 64) * 8);
    }

    for (int kt = 0; kt < K; kt += 64) {
#pragma unroll
        for (int i = 0; i < 8; ++i) {
            __builtin_amdgcn_global_load_lds(
                (const __attribute__((address_space(1))) unsigned int*)(gsrc[i] + kt),
                (__attribute__((address_space(3))) unsigned int*)(&lds[ldsoff[i]]),
                16, 0, 0);
        }
        __syncthreads();
#pragma unroll
        for (int kc = 0; kc < 2; ++kc) {
            const int xo = (((kc * 4 + (lane >> 4)) ^ (lane & 7)) << 4);
            bf16x8 aop[4], bop[4];
#pragma unroll
            for (int f = 0; f < 4; ++f) {
                const int rA = wm * 64 + f * 16 + (lane & 15);
                bop[f] = *(const bf16x8*)((const char*)lds + rA * 128 + xo);
                const int rB = wn * 64 + f * 16 + (lane & 15);
                aop[f] = *(const bf16x8*)((const char*)lds + 16384 * 1 + rB * 128 + xo);
            }
#pragma unroll
            for (int fm = 0; fm < 4; ++fm)
#pragma unroll
                for (int fn = 0; fn < 4; ++fn)
                    acc[fm][fn] = __builtin_amdgcn_mfma_f32_16x16x32_bf16(
                        aop[fn], bop[fm], acc[fm][fn], 0, 0, 0);
        }
        __syncthreads();
    }

    const int mrow = m0 + wm * 64 + (lane & 15);
    const int ncol = n0 + wn * 64 + ((lane >> 4) * 4);
#pragma unroll
    for (int fm = 0; fm < 4; ++fm) {
#pragma unroll
        for (int fn = 0; fn < 4; ++fn) {
            f32x4 v = acc[fm][fn];
            unsigned int u0 = f2bf(v.x) | ((unsigned int)f2bf(v.y) << 16);
            unsigned int u1 = f2bf(v.z) | ((unsigned int)f2bf(v.w) << 16);
            uint2 pk = make_uint2(u0, u1);
            *(uint2*)&C[(size_t)(mrow + fm * 16) * ldc + ncol + fn * 16] = pk;
        }
    }
}

// ---------------- attention ----------------
// One wave per (k,h): wsf[k*6+h] = sum_c W[k,h*C+c]*asrc[h,c]; same for adst.
// Reads W once, computes both folds.
__global__ __launch_bounds__(64) void fold2_k(const float* __restrict__ W,
                                              const float* __restrict__ avs,
                                              const float* __restrict__ avd,
                                              float* __restrict__ wsf,
                                              float* __restrict__ wdf,
                                              int K, int C) {
    int bid = blockIdx.x;               // k*HEADS + h
    int k = bid / HEADS, h = bid % HEADS;
    int lane = threadIdx.x;
    const float* wr = W + (size_t)k * (HEADS * C) + h * C;
    const float* sr = avs + h * C;
    const float* dr = avd + h * C;
    float s = 0.f, d = 0.f;
    for (int c = lane; c < C; c += 64) {
        float w = wr[c];
        s += w * sr[c];
        d += w * dr[c];
    }
#pragma unroll
    for (int off = 32; off > 0; off >>= 1) {
        s += __shfl_xor(s, off);
        d += __shfl_xor(d, off);
    }
    if (lane == 0) { wsf[bid] = s; wdf[bid] = d; }
}

__global__ void proj_k(const unsigned short* __restrict__ t, const float* __restrict__ wsf,
                       const float* __restrict__ wdf, float* __restrict__ a_s,
                       float* __restrict__ a_d, int K) {
    int idx = blockIdx.x * blockDim.x + threadIdx.x;
    if (idx >= N_NODES * HEADS) return;
    int n = idx / HEADS, h = idx % HEADS;
    const unsigned short* tr = t + (size_t)n * K;
    float s = 0.f, d = 0.f;
    for (int k = 0; k < K; ++k) {
        float v = bf2f(tr[k]);
        s += v * wsf[k * HEADS + h];
        d += v * wdf[k * HEADS + h];
    }
    a_s[idx] = s; a_d[idx] = d;
}

__global__ void edge_logits_k(const int* __restrict__ srcv, const int* __restrict__ dstv,
                              const float* __restrict__ a_s, const float* __restrict__ a_d,
                              float* __restrict__ earr) {
    int idx = blockIdx.x * blockDim.x + threadIdx.x;
    if (idx >= N_EDGES * HEADS) return;
    int e = idx / HEADS, h = idx % HEADS;
    float v = a_s[srcv[e] * HEADS + h] + a_d[dstv[e] * HEADS + h];
    earr[idx] = v > 0.f ? v : NEG_SLOPE * v;
}

__global__ void softmax_k(const float* __restrict__ earr, const int* __restrict__ csr,
                          const int* __restrict__ offs, float* __restrict__ alpha) {
    int idx = blockIdx.x * blockDim.x + threadIdx.x;
    if (idx >= N_NODES * HEADS) return;
    int n = idx / HEADS, h = idx % HEADS;
    int r0 = offs[n], r1 = offs[n + 1];
    if (r0 == r1) return;
    float m = -1e30f;
    for (int i = r0; i < r1; ++i) m = fmaxf(m, earr[csr[i] * HEADS + h]);
    float denom = 0.f;
    for (int i = r0; i < r1; ++i) {
        float ex = __expf(earr[csr[i] * HEADS + h] - m);
        alpha[csr[i] * HEADS + h] = ex;
        denom += ex;
    }
    float rd = 1.f / denom;
    for (int i = r0; i < r1; ++i) alpha[csr[i] * HEADS + h] *= rd;
}

// ---------------- aggregation (x in bf16) ----------------
__global__ __launch_bounds__(256) void aggregate_k(const unsigned short* __restrict__ x,
                                                   const float* __restrict__ alpha,
                                                   const int* __restrict__ csr,
                                                   const int* __restrict__ offs,
                                                   const int* __restrict__ srcv,
                                                   unsigned short* __restrict__ tout,
                                                   int C, int ldx, int ld, int off) {
    int n = blockIdx.x;
    int c = blockIdx.y * 256 + threadIdx.x;
    if (c >= C) return;
    float acc = 0.f;
    int r0 = offs[n], r1 = offs[n + 1];
    for (int i = r0; i < r1; ++i) {
        int ee = csr[i];
        int s = srcv[ee];
        const unsigned short* xr = x + (size_t)s * ldx + c;
        const float* al = alpha + (size_t)ee * HEADS;
#pragma unroll
        for (int h = 0; h < HEADS; ++h) acc += al[h] * bf2f(xr[h * C]);
    }
    tout[(size_t)n * ld + off + c] = f2bf(selu_f(acc * (1.f / 6.f)));
}

__global__ void move_coords_k(const float* __restrict__ cprev, const float* __restrict__ alpha,
                              const int* __restrict__ csr, const int* __restrict__ offs,
                              const int* __restrict__ srcv, const int* __restrict__ bd,
                              float* __restrict__ cout, unsigned short* __restrict__ tnext,
                              int ld, int off) {
    int n = blockIdx.x * blockDim.x + threadIdx.x;
    if (n >= N_NODES) return;
    float cx, cy;
    if (bd[n] != 0) {
        cx = cprev[2 * n]; cy = cprev[2 * n + 1];
    } else {
        cx = 0.f; cy = 0.f;
        int r0 = offs[n], r1 = offs[n + 1];
        for (int i = r0; i < r1; ++i) {
            int ee = csr[i];
            int s = srcv[ee];
            const float* al = alpha + (size_t)ee * HEADS;
            float am = (al[0] + al[1] + al[2] + al[3] + al[4] + al[5]) * (1.f / 6.f);
            cx += am * cprev[2 * s];
            cy += am * cprev[2 * s + 1];
        }
    }
    cout[2 * n] = cx; cout[2 * n + 1] = cy;
    if (tnext) {
        tnext[(size_t)n * ld + off + 0] = f2bf(cx);
        tnext[(size_t)n * ld + off + 1] = f2bf(cy);
    }
}

__global__ void copy2_k(const float* __restrict__ srcc, unsigned short* __restrict__ t,
                        int ld, int off) {
    int n = blockIdx.x * blockDim.x + threadIdx.x;
    if (n < N_NODES) {
        t[(size_t)n * ld + off + 0] = f2bf(srcc[2 * n]);
        t[(size_t)n * ld + off + 1] = f2bf(srcc[2 * n + 1]);
    }
}

static inline int cdiv(int a, int b) { return (a + b - 1) / b; }

extern "C" void kernel_launch(void* const* d_in, const int* in_sizes, int n_in,
                              void* d_out, int out_size, void* d_ws, size_t ws_size,
                              hipStream_t stream) {
    const float* data = (const float*)d_in[0];
    const int* eidx = (const int*)d_in[1];
    const int* bd = (const int*)d_in[2];
    const float* W_lin = (const float*)d_in[4];
    const float* b_lin = (const float*)d_in[5];
    const float* Wl[4]  = {(const float*)d_in[6],  (const float*)d_in[9],
                           (const float*)d_in[12], (const float*)d_in[15]};
    const float* Asrc[4] = {(const float*)d_in[7],  (const float*)d_in[10],
                            (const float*)d_in[13], (const float*)d_in[16]};
    const float* Adst[4] = {(const float*)d_in[8],  (const float*)d_in[11],
                            (const float*)d_in[14], (const float*)d_in[17]};
    const int Kd[4] = {256, 512, 256, 128};
    const int Cd[4] = {508, 250, 120, 20};
    const int Npadd[4] = {3072, 1536, 768, 0};

    const int* srcv = eidx;
    const int* dstv = eidx + N_EDGES;

    char* p = (char*)d_ws;
    auto alloc = [&](size_t bytes) -> void* {
        void* r = (void*)p;
        p += (bytes + 255) & ~(size_t)255;
        return r;
    };
    unsigned short* tb1 = (unsigned short*)alloc((size_t)MPAD * 256 * 2);
    unsigned short* tb2 = (unsigned short*)alloc((size_t)MPAD * 512 * 2);
    unsigned short* tb3 = (unsigned short*)alloc((size_t)MPAD * 256 * 2);
    unsigned short* tb4 = (unsigned short*)alloc((size_t)MPAD * 128 * 2);
    unsigned short* xb  = (unsigned short*)alloc((size_t)MPAD * 3072 * 2);
    unsigned short* Wt  = (unsigned short*)alloc((size_t)3072 * 256 * 2);
    float* coords0 = (float*)alloc((size_t)N_NODES * 2 * 4);
    float* c1 = (float*)alloc((size_t)N_NODES * 2 * 4);
    float* c2 = (float*)alloc((size_t)N_NODES * 2 * 4);
    float* c3 = (float*)alloc((size_t)N_NODES * 2 * 4);
    float* a_s = (float*)alloc((size_t)N_NODES * HEADS * 4);
    float* a_d = (float*)alloc((size_t)N_NODES * HEADS * 4);
    float* earr = (float*)alloc((size_t)N_EDGES * HEADS * 4);
    float* alpha = (float*)alloc((size_t)N_EDGES * HEADS * 4);
    float* wsf = (float*)alloc((size_t)512 * HEADS * 4);
    float* wdf = (float*)alloc((size_t)512 * HEADS * 4);
    int* counts = (int*)alloc((size_t)N_NODES * 4);
    int* offs = (int*)alloc((size_t)(N_NODES + 1) * 4);
    int* cursor = (int*)alloc((size_t)N_NODES * 4);
    int* csr = (int*)alloc((size_t)N_EDGES * 4);

    hipMemsetAsync(counts, 0, N_NODES * sizeof(int), stream);
    hipMemsetAsync(cursor, 0, N_NODES * sizeof(int), stream);
    count_edges_k<<<cdiv(N_EDGES, 256), 256, 0, stream>>>(dstv, counts);
    scan_k<<<1, 1024, 0, stream>>>(counts, offs);
    fill_csr_k<<<cdiv(N_EDGES, 256), 256, 0, stream>>>(dstv, offs, cursor, csr);

    init_coords_k<<<cdiv(N_NODES, 256), 256, 0, stream>>>(data, coords0, tb1);
    lin_k<<<cdiv(N_NODES * 254, 256), 256, 0, stream>>>(data, W_lin, b_lin, tb1);

    unsigned short* tin[4]   = {tb1, tb2, tb3, tb4};
    unsigned short* tnext[4] = {tb2, tb3, tb4, nullptr};
    int ldn[4]  = {512, 256, 128, 0};
    int foff[4] = {4, 6, 8, 0};
    float* cprev[4] = {coords0, c1, c2, c3};
    float* cout[4]  = {c1, c2, c3, (float*)d_out};

    for (int l = 0; l < 4; ++l) {
        int K = Kd[l], C = Cd[l], HC = HEADS * C, Npad = Npadd[l];
        fold2_k<<<K * HEADS, 64, 0, stream>>>(Wl[l], Asrc[l], Adst[l], wsf, wdf, K, C);
        proj_k<<<cdiv(N_NODES * HEADS, 256), 256, 0, stream>>>(tin[l], wsf, wdf, a_s, a_d, K);
        edge_logits_k<<<cdiv(N_EDGES * HEADS, 256), 256, 0, stream>>>(srcv, dstv, a_s, a_d, earr);
        softmax_k<<<cdiv(N_NODES * HEADS, 256), 256, 0, stream>>>(earr, csr, offs, alpha);

        if (l < 3) {
            convw_k<<<cdiv(K * Npad, 256), 256, 0, stream>>>(Wl[l], Wt, K, HC, Npad);
            gemm_bf16_mfma<<<dim3(Npad / 128, MPAD / 128), 256, 0, stream>>>(
                tin[l], Wt, xb, K, Npad);
            aggregate_k<<<dim3(N_NODES, cdiv(C, 256)), 256, 0, stream>>>(
                xb, alpha, csr, offs, srcv, tnext[l], C, Npad, ldn[l], foff[l]);
        }
        move_coords_k<<<cdiv(N_NODES, 256), 256, 0, stream>>>(
            cprev[l], alpha, csr, offs, srcv, bd, cout[l], tnext[l], ldn[l], 0);
        if (l == 0) {
            copy2_k<<<cdiv(N_NODES, 256), 256, 0, stream>>>(coords0, tb2, 512, 2);
        } else if (l == 1) {
            copy2_k<<<cdiv(N_NODES, 256), 256, 0, stream>>>(c1, tb3, 256, 2);
            copy2_k<<<cdiv(N_NODES, 256), 256, 0, stream>>>(coords0, tb3, 256, 4);
        } else if (l == 2) {
            copy2_k<<<cdiv(N_NODES, 256), 256, 0, stream>>>(c2, tb4, 128, 2);
            copy2_k<<<cdiv(N_NODES, 256), 256, 0, stream>>>(c1, tb4, 128, 4);
            copy2_k<<<cdiv(N_NODES, 256), 256, 0, stream>>>(coords0, tb4, 128, 6);
        }
    }
}

// Round 5
// 532.409 us; speedup vs baseline: 2.7893x; 1.2631x over previous
//
#include <hip/hip_runtime.h>
#include <hip/hip_bf16.h>

#define N_NODES 10000
#define N_EDGES 70000
#define HEADS 6
#define MPAD 10112            // ceil(10000/128)*128
#define SELU_SCALE 1.0507009873554805f
#define SELU_ALPHA  1.6732632423543772f
#define NEG_SLOPE 0.2f

typedef __attribute__((ext_vector_type(8))) __bf16 bf16x8;
typedef __attribute__((ext_vector_type(4))) float f32x4;

__device__ __forceinline__ float selu_f(float x) {
    return x > 0.f ? SELU_SCALE * x : SELU_SCALE * SELU_ALPHA * (__expf(x) - 1.f);
}
__device__ __forceinline__ unsigned short f2bf(float f) {
    __hip_bfloat16 h = __float2bfloat16(f);
    return __builtin_bit_cast(unsigned short, h);
}
__device__ __forceinline__ float bf2f(unsigned short u) {
    unsigned int x = ((unsigned int)u) << 16;
    return __builtin_bit_cast(float, x);
}

// ---------------- CSR build ----------------
__global__ void count_edges_k(const int* __restrict__ dstv, int* __restrict__ counts) {
    int e = blockIdx.x * blockDim.x + threadIdx.x;
    if (e < N_EDGES) atomicAdd(&counts[dstv[e]], 1);
}

__global__ __launch_bounds__(1024) void scan_k(const int* __restrict__ counts, int* __restrict__ offs) {
    __shared__ int part[1024];
    int tid = threadIdx.x;
    const int per = (N_NODES + 1023) / 1024;  // 10
    int start = tid * per;
    int s = 0;
    for (int i = 0; i < per; ++i) { int idx = start + i; if (idx < N_NODES) s += counts[idx]; }
    part[tid] = s;
    __syncthreads();
    for (int off = 1; off < 1024; off <<= 1) {
        int v = (tid >= off) ? part[tid - off] : 0;
        __syncthreads();
        part[tid] += v;
        __syncthreads();
    }
    int run = part[tid] - s;
    for (int i = 0; i < per; ++i) {
        int idx = start + i;
        if (idx < N_NODES) { offs[idx] = run; run += counts[idx]; }
    }
    if (tid == 0) offs[N_NODES] = part[1023];
}

__global__ void fill_csr_k(const int* __restrict__ dstv, const int* __restrict__ offs,
                           int* __restrict__ cursor, int* __restrict__ csr) {
    int e = blockIdx.x * blockDim.x + threadIdx.x;
    if (e < N_EDGES) {
        int d = dstv[e];
        int pos = atomicAdd(&cursor[d], 1);
        csr[offs[d] + pos] = e;
    }
}

// ---------------- input prep ----------------
__global__ void init_coords_k(const float* __restrict__ data, float* __restrict__ coords0,
                              unsigned short* __restrict__ t1) {
    int n = blockIdx.x * blockDim.x + threadIdx.x;
    if (n < N_NODES) {
        float x = data[n * 10 + 0], y = data[n * 10 + 1];
        coords0[2 * n] = x; coords0[2 * n + 1] = y;
        t1[(size_t)n * 256 + 0] = f2bf(x); t1[(size_t)n * 256 + 1] = f2bf(y);
    }
}

__global__ void lin_k(const float* __restrict__ data, const float* __restrict__ W,
                      const float* __restrict__ b, unsigned short* __restrict__ t1) {
    int idx = blockIdx.x * blockDim.x + threadIdx.x;
    if (idx >= N_NODES * 254) return;
    int n = idx / 254, c = idx % 254;
    float acc = b[c];
    const float* dr = data + (size_t)n * 10;
#pragma unroll
    for (int k = 0; k < 10; ++k) acc += dr[k] * W[k * 254 + c];
    t1[(size_t)n * 256 + 2 + c] = f2bf(selu_f(acc));
}

// ---------------- W convert+transpose: W[K][HC] f32 -> Wt[Npad][K] bf16 ----------------
__global__ void convw_k(const float* __restrict__ W, unsigned short* __restrict__ Wt,
                        int K, int HC, int Npad) {
    int idx = blockIdx.x * blockDim.x + threadIdx.x;
    if (idx >= K * Npad) return;
    int k = idx / Npad, n = idx % Npad;           // coalesced read of W row
    float v = (n < HC) ? W[(size_t)k * HC + n] : 0.f;
    Wt[(size_t)n * K + k] = f2bf(v);
}

// ---------------- bf16 MFMA GEMM: C[Mpad][Npad] = A[Mpad][K] * Wt[Npad][K]^T ----------------
__global__ __launch_bounds__(256) void gemm_bf16_mfma(
    const unsigned short* __restrict__ A,   // bf16 [MPAD][K]
    const unsigned short* __restrict__ Bt,  // bf16 [Npad][K]
    unsigned short* __restrict__ C,         // bf16 [MPAD][ldc]
    int K, int ldc) {
    __shared__ unsigned short lds[16384];   // 32 KB: A tile [128][64] + B tile [128][64]
    const int tid = threadIdx.x;
    const int lane = tid & 63, wid = tid >> 6;
    const int wm = wid >> 1, wn = wid & 1;
    const int m0 = blockIdx.y * 128;
    const int n0 = blockIdx.x * 128;

    f32x4 acc[4][4] = {};   // acc[fm][fn]

    const unsigned short* gsrc[8];
    unsigned ldsoff[8];
#pragma unroll
    for (int i = 0; i < 8; ++i) {
        const int half = i >> 2;                    // 0 = A-tile, 1 = B-tile
        const int slot = (i & 3) * 256 + tid;       // 16B slot within tile
        const int r = slot >> 3;                    // tile row (0..127)
        const int c16 = slot & 7;                   // 16B column slot
        const int ksl = c16 ^ (r & 7);              // inverse-swizzled source k-slot
        gsrc[i] = (half ? (Bt + (size_t)(n0 + r) * K) : (A + (size_t)(m0 + r) * K)) + ksl * 8;
        ldsoff[i] = (unsigned)(half * 8192 + ((i & 3) * 256 + wid * 64) * 8);
    }

    for (int kt = 0; kt < K; kt += 64) {
#pragma unroll
        for (int i = 0; i < 8; ++i) {
            __builtin_amdgcn_global_load_lds(
                (const __attribute__((address_space(1))) unsigned int*)(gsrc[i] + kt),
                (__attribute__((address_space(3))) unsigned int*)(&lds[ldsoff[i]]),
                16, 0, 0);
        }
        __syncthreads();
#pragma unroll
        for (int kc = 0; kc < 2; ++kc) {
            const int xo = (((kc * 4 + (lane >> 4)) ^ (lane & 7)) << 4);
            bf16x8 aop[4], bop[4];
#pragma unroll
            for (int f = 0; f < 4; ++f) {
                const int rA = wm * 64 + f * 16 + (lane & 15);
                bop[f] = *(const bf16x8*)((const char*)lds + rA * 128 + xo);
                const int rB = wn * 64 + f * 16 + (lane & 15);
                aop[f] = *(const bf16x8*)((const char*)lds + 16384 * 1 + rB * 128 + xo);
            }
#pragma unroll
            for (int fm = 0; fm < 4; ++fm)
#pragma unroll
                for (int fn = 0; fn < 4; ++fn)
                    acc[fm][fn] = __builtin_amdgcn_mfma_f32_16x16x32_bf16(
                        aop[fn], bop[fm], acc[fm][fn], 0, 0, 0);
        }
        __syncthreads();
    }

    const int mrow = m0 + wm * 64 + (lane & 15);
    const int ncol = n0 + wn * 64 + ((lane >> 4) * 4);
#pragma unroll
    for (int fm = 0; fm < 4; ++fm) {
#pragma unroll
        for (int fn = 0; fn < 4; ++fn) {
            f32x4 v = acc[fm][fn];
            unsigned int u0 = f2bf(v.x) | ((unsigned int)f2bf(v.y) << 16);
            unsigned int u1 = f2bf(v.z) | ((unsigned int)f2bf(v.w) << 16);
            uint2 pk = make_uint2(u0, u1);
            *(uint2*)&C[(size_t)(mrow + fm * 16) * ldc + ncol + fn * 16] = pk;
        }
    }
}

// ---------------- attention ----------------
// One wave per (k,h): wsf[k*6+h] = sum_c W[k,h*C+c]*asrc[h,c]; same for adst.
__global__ __launch_bounds__(64) void fold2_k(const float* __restrict__ W,
                                              const float* __restrict__ avs,
                                              const float* __restrict__ avd,
                                              float* __restrict__ wsf,
                                              float* __restrict__ wdf,
                                              int K, int C) {
    int bid = blockIdx.x;               // k*HEADS + h
    int k = bid / HEADS, h = bid % HEADS;
    int lane = threadIdx.x;
    const float* wr = W + (size_t)k * (HEADS * C) + h * C;
    const float* sr = avs + h * C;
    const float* dr = avd + h * C;
    float s = 0.f, d = 0.f;
    for (int c = lane; c < C; c += 64) {
        float w = wr[c];
        s += w * sr[c];
        d += w * dr[c];
    }
#pragma unroll
    for (int off = 32; off > 0; off >>= 1) {
        s += __shfl_xor(s, off);
        d += __shfl_xor(d, off);
    }
    if (lane == 0) { wsf[bid] = s; wdf[bid] = d; }
}

// One wave per node: lane owns K/64 contiguous k's via a single vector load,
// accumulates 12 dots (6 heads x src/dst), butterfly-reduces, lane 0 writes.
__global__ __launch_bounds__(256) void proj2_k(const unsigned short* __restrict__ t,
                                               const float* __restrict__ wsf,
                                               const float* __restrict__ wdf,
                                               float* __restrict__ a_s,
                                               float* __restrict__ a_d, int K) {
    const int wv = threadIdx.x >> 6;
    const int lane = threadIdx.x & 63;
    const int n = blockIdx.x * 4 + wv;
    if (n >= N_NODES) return;
    const unsigned short* tr = t + (size_t)n * K;
    const int kpl = K >> 6;             // 2, 4, or 8 elems per lane
    const int k0 = lane * kpl;

    unsigned int buf[4] = {0u, 0u, 0u, 0u};
    if (kpl == 8) {
        uint4 u = *(const uint4*)(tr + k0);
        buf[0] = u.x; buf[1] = u.y; buf[2] = u.z; buf[3] = u.w;
    } else if (kpl == 4) {
        uint2 u = *(const uint2*)(tr + k0);
        buf[0] = u.x; buf[1] = u.y;
    } else {
        buf[0] = *(const unsigned int*)(tr + k0);
    }

    float s[HEADS] = {}, d[HEADS] = {};
#pragma unroll
    for (int j = 0; j < 8; ++j) {
        if (j >= kpl) break;
        unsigned int w = buf[j >> 1];
        unsigned short u = (j & 1) ? (unsigned short)(w >> 16) : (unsigned short)(w & 0xffff);
        float v = bf2f(u);
        const float* ws = wsf + (size_t)(k0 + j) * HEADS;
        const float* wd = wdf + (size_t)(k0 + j) * HEADS;
#pragma unroll
        for (int h = 0; h < HEADS; ++h) {
            s[h] += v * ws[h];
            d[h] += v * wd[h];
        }
    }
#pragma unroll
    for (int off = 32; off > 0; off >>= 1) {
#pragma unroll
        for (int h = 0; h < HEADS; ++h) {
            s[h] += __shfl_xor(s[h], off);
            d[h] += __shfl_xor(d[h], off);
        }
    }
    if (lane == 0) {
#pragma unroll
        for (int h = 0; h < HEADS; ++h) {
            a_s[n * HEADS + h] = s[h];
            a_d[n * HEADS + h] = d[h];
        }
    }
}

__global__ void edge_logits_k(const int* __restrict__ srcv, const int* __restrict__ dstv,
                              const float* __restrict__ a_s, const float* __restrict__ a_d,
                              float* __restrict__ earr) {
    int idx = blockIdx.x * blockDim.x + threadIdx.x;
    if (idx >= N_EDGES * HEADS) return;
    int e = idx / HEADS, h = idx % HEADS;
    float v = a_s[srcv[e] * HEADS + h] + a_d[dstv[e] * HEADS + h];
    earr[idx] = v > 0.f ? v : NEG_SLOPE * v;
}

__global__ void softmax_k(const float* __restrict__ earr, const int* __restrict__ csr,
                          const int* __restrict__ offs, float* __restrict__ alpha) {
    int idx = blockIdx.x * blockDim.x + threadIdx.x;
    if (idx >= N_NODES * HEADS) return;
    int n = idx / HEADS, h = idx % HEADS;
    int r0 = offs[n], r1 = offs[n + 1];
    if (r0 == r1) return;
    float m = -1e30f;
    for (int i = r0; i < r1; ++i) m = fmaxf(m, earr[csr[i] * HEADS + h]);
    float denom = 0.f;
    for (int i = r0; i < r1; ++i) {
        float ex = __expf(earr[csr[i] * HEADS + h] - m);
        alpha[csr[i] * HEADS + h] = ex;
        denom += ex;
    }
    float rd = 1.f / denom;
    for (int i = r0; i < r1; ++i) alpha[csr[i] * HEADS + h] *= rd;
}

// ---------------- aggregation (x in bf16) ----------------
__global__ __launch_bounds__(256) void aggregate_k(const unsigned short* __restrict__ x,
                                                   const float* __restrict__ alpha,
                                                   const int* __restrict__ csr,
                                                   const int* __restrict__ offs,
                                                   const int* __restrict__ srcv,
                                                   unsigned short* __restrict__ tout,
                                                   int C, int ldx, int ld, int off) {
    int n = blockIdx.x;
    int c = blockIdx.y * 256 + threadIdx.x;
    if (c >= C) return;
    float acc = 0.f;
    int r0 = offs[n], r1 = offs[n + 1];
    for (int i = r0; i < r1; ++i) {
        int ee = csr[i];
        int s = srcv[ee];
        const unsigned short* xr = x + (size_t)s * ldx + c;
        const float* al = alpha + (size_t)ee * HEADS;
#pragma unroll
        for (int h = 0; h < HEADS; ++h) acc += al[h] * bf2f(xr[h * C]);
    }
    tout[(size_t)n * ld + off + c] = f2bf(selu_f(acc * (1.f / 6.f)));
}

__global__ void move_coords_k(const float* __restrict__ cprev, const float* __restrict__ alpha,
                              const int* __restrict__ csr, const int* __restrict__ offs,
                              const int* __restrict__ srcv, const int* __restrict__ bd,
                              float* __restrict__ cout, unsigned short* __restrict__ tnext,
                              int ld, int off) {
    int n = blockIdx.x * blockDim.x + threadIdx.x;
    if (n >= N_NODES) return;
    float cx, cy;
    if (bd[n] != 0) {
        cx = cprev[2 * n]; cy = cprev[2 * n + 1];
    } else {
        cx = 0.f; cy = 0.f;
        int r0 = offs[n], r1 = offs[n + 1];
        for (int i = r0; i < r1; ++i) {
            int ee = csr[i];
            int s = srcv[ee];
            const float* al = alpha + (size_t)ee * HEADS;
            float am = (al[0] + al[1] + al[2] + al[3] + al[4] + al[5]) * (1.f / 6.f);
            cx += am * cprev[2 * s];
            cy += am * cprev[2 * s + 1];
        }
    }
    cout[2 * n] = cx; cout[2 * n + 1] = cy;
    if (tnext) {
        tnext[(size_t)n * ld + off + 0] = f2bf(cx);
        tnext[(size_t)n * ld + off + 1] = f2bf(cy);
    }
}

__global__ void copy2_k(const float* __restrict__ srcc, unsigned short* __restrict__ t,
                        int ld, int off) {
    int n = blockIdx.x * blockDim.x + threadIdx.x;
    if (n < N_NODES) {
        t[(size_t)n * ld + off + 0] = f2bf(srcc[2 * n]);
        t[(size_t)n * ld + off + 1] = f2bf(srcc[2 * n + 1]);
    }
}

static inline int cdiv(int a, int b) { return (a + b - 1) / b; }

extern "C" void kernel_launch(void* const* d_in, const int* in_sizes, int n_in,
                              void* d_out, int out_size, void* d_ws, size_t ws_size,
                              hipStream_t stream) {
    const float* data = (const float*)d_in[0];
    const int* eidx = (const int*)d_in[1];
    const int* bd = (const int*)d_in[2];
    const float* W_lin = (const float*)d_in[4];
    const float* b_lin = (const float*)d_in[5];
    const float* Wl[4]  = {(const float*)d_in[6],  (const float*)d_in[9],
                           (const float*)d_in[12], (const float*)d_in[15]};
    const float* Asrc[4] = {(const float*)d_in[7],  (const float*)d_in[10],
                            (const float*)d_in[13], (const float*)d_in[16]};
    const float* Adst[4] = {(const float*)d_in[8],  (const float*)d_in[11],
                            (const float*)d_in[14], (const float*)d_in[17]};
    const int Kd[4] = {256, 512, 256, 128};
    const int Cd[4] = {508, 250, 120, 20};
    const int Npadd[4] = {3072, 1536, 768, 0};

    const int* srcv = eidx;
    const int* dstv = eidx + N_EDGES;

    char* p = (char*)d_ws;
    auto alloc = [&](size_t bytes) -> void* {
        void* r = (void*)p;
        p += (bytes + 255) & ~(size_t)255;
        return r;
    };
    unsigned short* tb1 = (unsigned short*)alloc((size_t)MPAD * 256 * 2);
    unsigned short* tb2 = (unsigned short*)alloc((size_t)MPAD * 512 * 2);
    unsigned short* tb3 = (unsigned short*)alloc((size_t)MPAD * 256 * 2);
    unsigned short* tb4 = (unsigned short*)alloc((size_t)MPAD * 128 * 2);
    unsigned short* xb  = (unsigned short*)alloc((size_t)MPAD * 3072 * 2);
    unsigned short* Wt  = (unsigned short*)alloc((size_t)3072 * 256 * 2);
    float* coords0 = (float*)alloc((size_t)N_NODES * 2 * 4);
    float* c1 = (float*)alloc((size_t)N_NODES * 2 * 4);
    float* c2 = (float*)alloc((size_t)N_NODES * 2 * 4);
    float* c3 = (float*)alloc((size_t)N_NODES * 2 * 4);
    float* a_s = (float*)alloc((size_t)N_NODES * HEADS * 4);
    float* a_d = (float*)alloc((size_t)N_NODES * HEADS * 4);
    float* earr = (float*)alloc((size_t)N_EDGES * HEADS * 4);
    float* alpha = (float*)alloc((size_t)N_EDGES * HEADS * 4);
    float* wsf = (float*)alloc((size_t)512 * HEADS * 4);
    float* wdf = (float*)alloc((size_t)512 * HEADS * 4);
    int* counts = (int*)alloc((size_t)N_NODES * 4);
    int* offs = (int*)alloc((size_t)(N_NODES + 1) * 4);
    int* cursor = (int*)alloc((size_t)N_NODES * 4);
    int* csr = (int*)alloc((size_t)N_EDGES * 4);

    hipMemsetAsync(counts, 0, N_NODES * sizeof(int), stream);
    hipMemsetAsync(cursor, 0, N_NODES * sizeof(int), stream);
    count_edges_k<<<cdiv(N_EDGES, 256), 256, 0, stream>>>(dstv, counts);
    scan_k<<<1, 1024, 0, stream>>>(counts, offs);
    fill_csr_k<<<cdiv(N_EDGES, 256), 256, 0, stream>>>(dstv, offs, cursor, csr);

    init_coords_k<<<cdiv(N_NODES, 256), 256, 0, stream>>>(data, coords0, tb1);
    lin_k<<<cdiv(N_NODES * 254, 256), 256, 0, stream>>>(data, W_lin, b_lin, tb1);

    unsigned short* tin[4]   = {tb1, tb2, tb3, tb4};
    unsigned short* tnext[4] = {tb2, tb3, tb4, nullptr};
    int ldn[4]  = {512, 256, 128, 0};
    int foff[4] = {4, 6, 8, 0};
    float* cprev[4] = {coords0, c1, c2, c3};
    float* cout[4]  = {c1, c2, c3, (float*)d_out};

    for (int l = 0; l < 4; ++l) {
        int K = Kd[l], C = Cd[l], HC = HEADS * C, Npad = Npadd[l];
        fold2_k<<<K * HEADS, 64, 0, stream>>>(Wl[l], Asrc[l], Adst[l], wsf, wdf, K, C);
        proj2_k<<<cdiv(N_NODES, 4), 256, 0, stream>>>(tin[l], wsf, wdf, a_s, a_d, K);
        edge_logits_k<<<cdiv(N_EDGES * HEADS, 256), 256, 0, stream>>>(srcv, dstv, a_s, a_d, earr);
        softmax_k<<<cdiv(N_NODES * HEADS, 256), 256, 0, stream>>>(earr, csr, offs, alpha);

        if (l < 3) {
            convw_k<<<cdiv(K * Npad, 256), 256, 0, stream>>>(Wl[l], Wt, K, HC, Npad);
            gemm_bf16_mfma<<<dim3(Npad / 128, MPAD / 128), 256, 0, stream>>>(
                tin[l], Wt, xb, K, Npad);
            aggregate_k<<<dim3(N_NODES, cdiv(C, 256)), 256, 0, stream>>>(
                xb, alpha, csr, offs, srcv, tnext[l], C, Npad, ldn[l], foff[l]);
        }
        move_coords_k<<<cdiv(N_NODES, 256), 256, 0, stream>>>(
            cprev[l], alpha, csr, offs, srcv, bd, cout[l], tnext[l], ldn[l], 0);
        if (l == 0) {
            copy2_k<<<cdiv(N_NODES, 256), 256, 0, stream>>>(coords0, tb2, 512, 2);
        } else if (l == 1) {
            copy2_k<<<cdiv(N_NODES, 256), 256, 0, stream>>>(c1, tb3, 256, 2);
            copy2_k<<<cdiv(N_NODES, 256), 256, 0, stream>>>(coords0, tb3, 256, 4);
        } else if (l == 2) {
            copy2_k<<<cdiv(N_NODES, 256), 256, 0, stream>>>(c2, tb4, 128, 2);
            copy2_k<<<cdiv(N_NODES, 256), 256, 0, stream>>>(c1, tb4, 128, 4);
            copy2_k<<<cdiv(N_NODES, 256), 256, 0, stream>>>(coords0, tb4, 128, 6);
        }
    }
}